// Round 4
// baseline (364.559 us; speedup 1.0000x reference)
//
#include <hip/hip_runtime.h>
#include <math.h>

#define ALPHA 0.2f
#define NEGV  -9000000000000000.0f
#define EPSV  1e-5f

static constexpr int Bn = 8;
static constexpr int Nn = 1024;
static constexpr int Fn = 512;
static constexpr int M  = Bn * Nn;   // 8192 rows total

__device__ inline float wave_reduce_sum(float v) {
#pragma unroll
    for (int off = 32; off; off >>= 1) v += __shfl_xor(v, off);
    return v;
}
__device__ inline float wave_reduce_max(float v) {
#pragma unroll
    for (int off = 32; off; off >>= 1) v = fmaxf(v, __shfl_xor(v, off));
    return v;
}

// ---------------------------------------------------------------------------
// K0: c1[fi] = sum_fo W1[fi][fo] * a[fo];  c2[fi] = sum_fo W2[fi][fo] * a[512+fo]
// grid 1024 blocks x 64 threads (1 wave per output element)
// ---------------------------------------------------------------------------
__global__ __launch_bounds__(64) void k_proj_w(const float* __restrict__ W1,
                                               const float* __restrict__ W2,
                                               const float* __restrict__ a,
                                               float* __restrict__ c) {
    int bid   = blockIdx.x;
    int which = bid >> 9;          // 0 -> c1, 1 -> c2
    int row   = bid & 511;
    const float* W  = which ? W2 : W1;
    const float* av = a + which * Fn;
    const float* wr = W + (size_t)row * Fn;
    int lane = threadIdx.x;
    float s = 0.f;
#pragma unroll
    for (int p = 0; p < 2; ++p) {
        float4 wv = *(const float4*)&wr[lane * 4 + p * 256];
        float4 a4 = *(const float4*)&av[lane * 4 + p * 256];
        s += wv.x * a4.x + wv.y * a4.y + wv.z * a4.z + wv.w * a4.w;
    }
    s = wave_reduce_sum(s);
    if (lane == 0) c[which * Fn + row] = s;
}

// ---------------------------------------------------------------------------
// K1: Wha[b*N+i] = dot(h1[b,i,:], c1);  Wta[b*N+j] = dot(h2[b,j,:], c2)
// grid (M/4, 2) x 256 threads (wave per row)
// ---------------------------------------------------------------------------
__global__ __launch_bounds__(256) void k_proj_h(const float* __restrict__ h1,
                                                const float* __restrict__ h2,
                                                const float* __restrict__ c,
                                                float* __restrict__ Wha,
                                                float* __restrict__ Wta) {
    int which = blockIdx.y;
    const float* h  = which ? h2 : h1;
    const float* cv = c + which * Fn;
    float* outp = which ? Wta : Wha;
    int wave = threadIdx.x >> 6, lane = threadIdx.x & 63;
    int row  = blockIdx.x * 4 + wave;
    const float* hr = h + (size_t)row * Fn;
    float s = 0.f;
#pragma unroll
    for (int p = 0; p < 2; ++p) {
        float4 hv = *(const float4*)&hr[lane * 8 + p * 4];
        float4 c4 = *(const float4*)&cv[lane * 8 + p * 4];
        s += hv.x * c4.x + hv.y * c4.y + hv.z * c4.z + hv.w * c4.w;
    }
    s = wave_reduce_sum(s);
    if (lane == 0) outp[row] = s;
}

// ---------------------------------------------------------------------------
// K2: Wv = h2 @ W3   (M x 512) = (M x 512)(512 x 512), fp32 tiled GEMM
// 128x128 block tile, BK=16, 256 threads, 8x8 per thread.
// Software-pipelined: issue next tile's global loads BEFORE computing current
// tile, so ~600-900cy HBM/L2 latency hides under the ~2048cy FMA phase.
// ---------------------------------------------------------------------------
__global__ __launch_bounds__(256) void k_gemm(const float* __restrict__ A,
                                              const float* __restrict__ Bw,
                                              float* __restrict__ C,
                                              int K, int Ncols) {
    __shared__ __attribute__((aligned(16))) float As[16][132]; // [k][m] transposed
    __shared__ __attribute__((aligned(16))) float Bs[16][128]; // [k][n]
    int t  = threadIdx.x;
    int tx = t & 15, ty = t >> 4;
    int i0 = blockIdx.x * 128;
    int f0 = blockIdx.y * 128;
    float acc[8][8] = {};
    const int nkt = K / 16;

    float4 areg[2], breg[2];
    auto load_tile = [&](int kt) {
#pragma unroll
        for (int p = 0; p < 2; ++p) {
            int v  = p * 256 + t;
            areg[p] = *(const float4*)&A[(size_t)(i0 + (v >> 2)) * K + kt * 16 + (v & 3) * 4];
            breg[p] = *(const float4*)&Bw[(size_t)(kt * 16 + (v >> 5)) * Ncols + f0 + (v & 31) * 4];
        }
    };
    load_tile(0);
    for (int kt = 0; kt < nkt; ++kt) {
        __syncthreads();               // previous compute done reading LDS
#pragma unroll
        for (int p = 0; p < 2; ++p) {  // regs -> LDS (vmcnt wait lands here)
            int v = p * 256 + t;
            int row = v >> 2, kc = (v & 3) * 4;
            As[kc + 0][row] = areg[p].x;
            As[kc + 1][row] = areg[p].y;
            As[kc + 2][row] = areg[p].z;
            As[kc + 3][row] = areg[p].w;
            *(float4*)&Bs[v >> 5][(v & 31) * 4] = breg[p];
        }
        __syncthreads();
        if (kt + 1 < nkt) load_tile(kt + 1);   // in flight during compute
#pragma unroll
        for (int k = 0; k < 16; ++k) {
            float4 a0 = *(float4*)&As[k][ty * 8];
            float4 a1 = *(float4*)&As[k][ty * 8 + 4];
            float4 b0 = *(float4*)&Bs[k][tx * 8];
            float4 b1 = *(float4*)&Bs[k][tx * 8 + 4];
            float av[8] = {a0.x, a0.y, a0.z, a0.w, a1.x, a1.y, a1.z, a1.w};
            float bv[8] = {b0.x, b0.y, b0.z, b0.w, b1.x, b1.y, b1.z, b1.w};
#pragma unroll
            for (int i = 0; i < 8; ++i)
#pragma unroll
                for (int j = 0; j < 8; ++j)
                    acc[i][j] = fmaf(av[i], bv[j], acc[i][j]);
        }
    }
#pragma unroll
    for (int i = 0; i < 8; ++i) {
        float4 o0 = {acc[i][0], acc[i][1], acc[i][2], acc[i][3]};
        float4 o1 = {acc[i][4], acc[i][5], acc[i][6], acc[i][7]};
        size_t off = (size_t)(i0 + ty * 8 + i) * Ncols + f0 + tx * 8;
        *(float4*)&C[off]     = o0;
        *(float4*)&C[off + 4] = o1;
    }
}

// ---------------------------------------------------------------------------
// K3: per-row softmax stats over masked leaky scores; stat = (m, 1/s)
// grid M x 256 threads, each thread handles 4 j's
// ---------------------------------------------------------------------------
__global__ __launch_bounds__(256) void k_stats(const int* __restrict__ adj,
                                               const float* __restrict__ Wha,
                                               const float* __restrict__ Wta,
                                               float2* __restrict__ stat) {
    int bi = blockIdx.x;
    int b = bi >> 10, i = bi & 1023;
    const int*   arow = adj + ((size_t)b * Nn + i) * Nn;
    const float* wt   = Wta + b * Nn;
    float whai = Wha[bi];
    int t = threadIdx.x;
    int4   av = *(const int4*)&arow[t * 4];
    float4 wv = *(const float4*)&wt[t * 4];
    float e[4];
    {
        float x;
        x = whai + wv.x; x = x > 0.f ? x : ALPHA * x; e[0] = av.x > 0 ? x : NEGV;
        x = whai + wv.y; x = x > 0.f ? x : ALPHA * x; e[1] = av.y > 0 ? x : NEGV;
        x = whai + wv.z; x = x > 0.f ? x : ALPHA * x; e[2] = av.z > 0 ? x : NEGV;
        x = whai + wv.w; x = x > 0.f ? x : ALPHA * x; e[3] = av.w > 0 ? x : NEGV;
    }
    float m4 = fmaxf(fmaxf(e[0], e[1]), fmaxf(e[2], e[3]));
    __shared__ float redm[4], reds[4];
    int wave = t >> 6, lane = t & 63;
    float m = wave_reduce_max(m4);
    if (lane == 0) redm[wave] = m;
    __syncthreads();
    m = fmaxf(fmaxf(redm[0], redm[1]), fmaxf(redm[2], redm[3]));
    float s4 = __expf(e[0] - m) + __expf(e[1] - m) + __expf(e[2] - m) + __expf(e[3] - m);
    float s = wave_reduce_sum(s4);
    if (lane == 0) reds[wave] = s;
    __syncthreads();
    if (t == 0) {
        s = reds[0] + reds[1] + reds[2] + reds[3];
        stat[bi] = make_float2(m, 1.0f / s);
    }
}

// ---------------------------------------------------------------------------
// K4: h' = attention @ Wv, attention generated on the fly per K-tile.
// Same 128x128x16 tile as K2, software-pipelined: adj/Wta/Wv loads for tile
// kt+1 are issued before computing tile kt; exp()-based att generation runs
// in the LDS-write phase (consumes the loads issued one iteration earlier).
// grid (N/128, F/128, B)
// ---------------------------------------------------------------------------
__global__ __launch_bounds__(256) void k_attn_gemm(const int* __restrict__ adj,
                                                   const float* __restrict__ Wha,
                                                   const float* __restrict__ Wta,
                                                   const float2* __restrict__ stat,
                                                   const float* __restrict__ Wv,
                                                   float* __restrict__ outp) {
    __shared__ __attribute__((aligned(16))) float As[16][132];
    __shared__ __attribute__((aligned(16))) float Bs[16][128];
    int t  = threadIdx.x;
    int tx = t & 15, ty = t >> 4;
    int b  = blockIdx.z;
    int i0 = blockIdx.x * 128, f0 = blockIdx.y * 128;
    int r  = t >> 1, kh = (t & 1) * 8;   // att-gen mapping: 2 threads/row, 8 k's each
    float  whai = Wha[b * Nn + i0 + r];
    float2 st   = stat[b * Nn + i0 + r];
    const int*   arow = adj + ((size_t)b * Nn + (i0 + r)) * Nn;
    const float* wt   = Wta + b * Nn;
    const float* WvB  = Wv + (size_t)b * Nn * Fn;
    float acc[8][8] = {};

    int4 a0, a1; float4 w0, w1; float4 breg[2];
    auto load_tile = [&](int kt) {
        int j0 = kt * 16;
        a0 = *(const int4*)&arow[j0 + kh];
        a1 = *(const int4*)&arow[j0 + kh + 4];
        w0 = *(const float4*)&wt[j0 + kh];
        w1 = *(const float4*)&wt[j0 + kh + 4];
#pragma unroll
        for (int p = 0; p < 2; ++p) {
            int v = p * 256 + t;
            breg[p] = *(const float4*)&WvB[(size_t)(j0 + (v >> 5)) * Fn + f0 + (v & 31) * 4];
        }
    };
    load_tile(0);
    for (int kt = 0; kt < Nn / 16; ++kt) {
        float att[8];
        {
            auto attf = [&](int adjv, float wtj) {
                float x = whai + wtj;
                x = x > 0.f ? x : ALPHA * x;
                float e = adjv > 0 ? x : NEGV;
                return __expf(e - st.x) * st.y;
            };
            att[0] = attf(a0.x, w0.x); att[1] = attf(a0.y, w0.y);
            att[2] = attf(a0.z, w0.z); att[3] = attf(a0.w, w0.w);
            att[4] = attf(a1.x, w1.x); att[5] = attf(a1.y, w1.y);
            att[6] = attf(a1.z, w1.z); att[7] = attf(a1.w, w1.w);
        }
        __syncthreads();               // previous compute done reading LDS
#pragma unroll
        for (int m = 0; m < 8; ++m) As[kh + m][r] = att[m];
#pragma unroll
        for (int p = 0; p < 2; ++p) {
            int v = p * 256 + t;
            *(float4*)&Bs[v >> 5][(v & 31) * 4] = breg[p];
        }
        __syncthreads();
        if (kt + 1 < Nn / 16) load_tile(kt + 1);   // in flight during compute
#pragma unroll
        for (int k = 0; k < 16; ++k) {
            float4 va0 = *(float4*)&As[k][ty * 8];
            float4 va1 = *(float4*)&As[k][ty * 8 + 4];
            float4 vb0 = *(float4*)&Bs[k][tx * 8];
            float4 vb1 = *(float4*)&Bs[k][tx * 8 + 4];
            float av[8] = {va0.x, va0.y, va0.z, va0.w, va1.x, va1.y, va1.z, va1.w};
            float bv[8] = {vb0.x, vb0.y, vb0.z, vb0.w, vb1.x, vb1.y, vb1.z, vb1.w};
#pragma unroll
            for (int i = 0; i < 8; ++i)
#pragma unroll
                for (int j = 0; j < 8; ++j)
                    acc[i][j] = fmaf(av[i], bv[j], acc[i][j]);
        }
    }
#pragma unroll
    for (int i = 0; i < 8; ++i) {
        float4 o0 = {acc[i][0], acc[i][1], acc[i][2], acc[i][3]};
        float4 o1 = {acc[i][4], acc[i][5], acc[i][6], acc[i][7]};
        size_t off = ((size_t)b * Nn + i0 + ty * 8 + i) * Fn + f0 + tx * 8;
        *(float4*)&outp[off]     = o0;
        *(float4*)&outp[off + 4] = o1;
    }
}

// ---------------------------------------------------------------------------
// K5: LayerNorm over F + exact GELU, in-place on d_out. grid M x 128 threads
// ---------------------------------------------------------------------------
__global__ __launch_bounds__(128) void k_ln_gelu(float* __restrict__ x,
                                                 const float* __restrict__ gamma,
                                                 const float* __restrict__ beta) {
    int row = blockIdx.x;
    float* xr = x + (size_t)row * Fn;
    int t = threadIdx.x;
    float4 v = *(float4*)&xr[t * 4];
    float s = v.x + v.y + v.z + v.w;
    float q = v.x * v.x + v.y * v.y + v.z * v.z + v.w * v.w;
    s = wave_reduce_sum(s);
    q = wave_reduce_sum(q);
    __shared__ float rs[2], rq[2];
    int wave = t >> 6, lane = t & 63;
    if (lane == 0) { rs[wave] = s; rq[wave] = q; }
    __syncthreads();
    s = rs[0] + rs[1];
    q = rq[0] + rq[1];
    float mu   = s * (1.0f / Fn);
    float var  = q * (1.0f / Fn) - mu * mu;
    float rstd = rsqrtf(var + EPSV);
    float4 g  = *(const float4*)&gamma[t * 4];
    float4 be = *(const float4*)&beta[t * 4];
    auto gel = [](float xx) { return 0.5f * xx * (1.0f + erff(xx * 0.70710678118f)); };
    float y0 = (v.x - mu) * rstd * g.x + be.x;
    float y1 = (v.y - mu) * rstd * g.y + be.y;
    float y2 = (v.z - mu) * rstd * g.z + be.z;
    float y3 = (v.w - mu) * rstd * g.w + be.w;
    float4 o = {gel(y0), gel(y1), gel(y2), gel(y3)};
    *(float4*)&xr[t * 4] = o;
}

// ---------------------------------------------------------------------------
extern "C" void kernel_launch(void* const* d_in, const int* in_sizes, int n_in,
                              void* d_out, int out_size, void* d_ws, size_t ws_size,
                              hipStream_t stream) {
    const float* h1    = (const float*)d_in[0];
    const float* h2    = (const float*)d_in[1];
    const int*   adj   = (const int*)d_in[2];
    const float* W1    = (const float*)d_in[3];
    const float* W2    = (const float*)d_in[4];
    const float* W3    = (const float*)d_in[5];
    const float* a     = (const float*)d_in[6];
    const float* gamma = (const float*)d_in[7];
    const float* beta  = (const float*)d_in[8];
    float* outp = (float*)d_out;
    float* ws   = (float*)d_ws;

    float*  Wv   = ws;                       // M*Fn floats = 16.8 MB
    float*  c    = Wv + (size_t)M * Fn;      // 1024
    float*  Wha  = c + 1024;                 // M
    float*  Wta  = Wha + M;                  // M
    float2* stat = (float2*)(Wta + M);       // M float2

    hipLaunchKernelGGL(k_proj_w, dim3(1024), dim3(64), 0, stream, W1, W2, a, c);
    hipLaunchKernelGGL(k_proj_h, dim3(M / 4, 2), dim3(256), 0, stream, h1, h2, c, Wha, Wta);
    hipLaunchKernelGGL(k_gemm, dim3(M / 128, Fn / 128), dim3(256), 0, stream, h2, W3, Wv, Fn, Fn);
    hipLaunchKernelGGL(k_stats, dim3(M), dim3(256), 0, stream, adj, Wha, Wta, stat);
    hipLaunchKernelGGL(k_attn_gemm, dim3(Nn / 128, Fn / 128, Bn), dim3(256), 0, stream,
                       adj, Wha, Wta, stat, Wv, outp);
    hipLaunchKernelGGL(k_ln_gelu, dim3(M), dim3(128), 0, stream, outp, gamma, beta);
}

// Round 6
// 264.165 us; speedup vs baseline: 1.3800x; 1.3800x over previous
//
#include <hip/hip_runtime.h>
#include <math.h>

#define ALPHA 0.2f
#define NEGV  -9000000000000000.0f
#define EPSV  1e-5f

static constexpr int Bn = 8;
static constexpr int Nn = 1024;
static constexpr int Fn = 512;
static constexpr int M  = Bn * Nn;   // 8192 rows total

typedef __attribute__((ext_vector_type(8))) short bf16x8;
typedef __attribute__((ext_vector_type(4))) float f32x4;

__device__ inline float wave_reduce_sum(float v) {
#pragma unroll
    for (int off = 32; off; off >>= 1) v += __shfl_xor(v, off);
    return v;
}
__device__ inline float wave_reduce_max(float v) {
#pragma unroll
    for (int off = 32; off; off >>= 1) v = fmaxf(v, __shfl_xor(v, off));
    return v;
}

__device__ inline unsigned short bf16_rne(float f) {
    union { float f; unsigned int u; } v; v.f = f;
    unsigned int r = v.u + 0x7FFFu + ((v.u >> 16) & 1u);
    return (unsigned short)(r >> 16);
}
__device__ inline float bf16_to_f(unsigned short h) {
    union { unsigned int u; float f; } v; v.u = (unsigned int)h << 16;
    return v.f;
}

// ---------------------------------------------------------------------------
// K-1: pack adj (int32 0/1) into bitmask words: pk[row*32 + w] bit q = adj[row*1024 + w*32+q] > 0
// grid 1024 x 256 (one thread per output word, reads 128B contiguous)
// ---------------------------------------------------------------------------
__global__ __launch_bounds__(256) void k_pack(const int* __restrict__ adj,
                                              unsigned int* __restrict__ pk) {
    int idx = blockIdx.x * 256 + threadIdx.x;       // word index, < M*32
    const int* p = adj + (size_t)idx * 32;
    unsigned int m = 0;
#pragma unroll
    for (int q = 0; q < 8; ++q) {
        int4 v = *(const int4*)&p[q * 4];
        m |= (unsigned)(v.x > 0) << (q * 4 + 0);
        m |= (unsigned)(v.y > 0) << (q * 4 + 1);
        m |= (unsigned)(v.z > 0) << (q * 4 + 2);
        m |= (unsigned)(v.w > 0) << (q * 4 + 3);
    }
    pk[idx] = m;
}

// ---------------------------------------------------------------------------
// K0: c1[fi] = sum_fo W1[fi][fo]*a[fo];  c2[fi] = sum_fo W2[fi][fo]*a[512+fo]
// ---------------------------------------------------------------------------
__global__ __launch_bounds__(64) void k_proj_w(const float* __restrict__ W1,
                                               const float* __restrict__ W2,
                                               const float* __restrict__ a,
                                               float* __restrict__ c) {
    int bid   = blockIdx.x;
    int which = bid >> 9;
    int row   = bid & 511;
    const float* W  = which ? W2 : W1;
    const float* av = a + which * Fn;
    const float* wr = W + (size_t)row * Fn;
    int lane = threadIdx.x;
    float s = 0.f;
#pragma unroll
    for (int p = 0; p < 2; ++p) {
        float4 wv = *(const float4*)&wr[lane * 4 + p * 256];
        float4 a4 = *(const float4*)&av[lane * 4 + p * 256];
        s += wv.x * a4.x + wv.y * a4.y + wv.z * a4.z + wv.w * a4.w;
    }
    s = wave_reduce_sum(s);
    if (lane == 0) c[which * Fn + row] = s;
}

// ---------------------------------------------------------------------------
// K1: Wha = h1 @ c1 ; Wta = h2 @ c2 (wave per row)
// ---------------------------------------------------------------------------
__global__ __launch_bounds__(256) void k_proj_h(const float* __restrict__ h1,
                                                const float* __restrict__ h2,
                                                const float* __restrict__ c,
                                                float* __restrict__ Wha,
                                                float* __restrict__ Wta) {
    int which = blockIdx.y;
    const float* h  = which ? h2 : h1;
    const float* cv = c + which * Fn;
    float* outp = which ? Wta : Wha;
    int wave = threadIdx.x >> 6, lane = threadIdx.x & 63;
    int row  = blockIdx.x * 4 + wave;
    const float* hr = h + (size_t)row * Fn;
    float s = 0.f;
#pragma unroll
    for (int p = 0; p < 2; ++p) {
        float4 hv = *(const float4*)&hr[lane * 8 + p * 4];
        float4 c4 = *(const float4*)&cv[lane * 8 + p * 4];
        s += hv.x * c4.x + hv.y * c4.y + hv.z * c4.z + hv.w * c4.w;
    }
    s = wave_reduce_sum(s);
    if (lane == 0) outp[row] = s;
}

// ---------------------------------------------------------------------------
// K2: Wv = h2 @ W3 via split-bf16 MFMA; outputs PRE-SPLIT bf16 hi/lo planes.
// Tile 128x128xBK32, 4 waves, each wave a 64x64 quadrant (4x4 frags 16x16).
// A split in-staging; products hi*hi + hi*lo + lo*hi accumulated in fp32.
// grid (M/128, Fn/128)
// ---------------------------------------------------------------------------
__global__ __launch_bounds__(256) void k_gemm_mfma(const float* __restrict__ A,
                                                   const float* __restrict__ Bw,
                                                   unsigned short* __restrict__ wv_hi,
                                                   unsigned short* __restrict__ wv_lo) {
    __shared__ __attribute__((aligned(16))) unsigned short a_hi[128 * 40];
    __shared__ __attribute__((aligned(16))) unsigned short a_lo[128 * 40];
    __shared__ __attribute__((aligned(16))) unsigned short b_hi[128 * 40];
    __shared__ __attribute__((aligned(16))) unsigned short b_lo[128 * 40];
    int t = threadIdx.x;
    int wave = t >> 6, lane = t & 63;
    int wr = wave >> 1, wc = wave & 1;
    int i0 = blockIdx.x * 128, f0 = blockIdx.y * 128;

    f32x4 zero = {0.f, 0.f, 0.f, 0.f};
    f32x4 acc[4][4];
#pragma unroll
    for (int mi = 0; mi < 4; ++mi)
#pragma unroll
        for (int nj = 0; nj < 4; ++nj) acc[mi][nj] = zero;

    int ar = t >> 1, ac = (t & 1) * 16;        // A: row 0..127, 16-col half
    int bk = t >> 3, bf = (t & 7) * 16;        // B: k-row 0..31, 16-col group
    const float* abase = A + (size_t)(i0 + ar) * Fn + ac;
    const float* bbase = Bw + (size_t)bk * Fn + f0 + bf;

    float4 areg[4], breg[4];
    auto gload = [&](int kt) {
        const float* ap = abase + kt * 32;
#pragma unroll
        for (int p = 0; p < 4; ++p) areg[p] = *(const float4*)(ap + p * 4);
        const float* bp = bbase + (size_t)kt * 32 * Fn;
#pragma unroll
        for (int p = 0; p < 4; ++p) breg[p] = *(const float4*)(bp + p * 4);
    };

    gload(0);
    const int nkt = Fn / 32;   // 16
    for (int kt = 0; kt < nkt; ++kt) {
        __syncthreads();
        // stage A (split, vectorized writes)
#pragma unroll
        for (int hf = 0; hf < 2; ++hf) {
            bf16x8 vh, vl;
#pragma unroll
            for (int q = 0; q < 8; ++q) {
                float f = ((const float*)&areg[hf * 2])[q];
                unsigned short hh = bf16_rne(f);
                vh[q] = (short)hh;
                vl[q] = (short)bf16_rne(f - bf16_to_f(hh));
            }
            *(bf16x8*)&a_hi[ar * 40 + ac + hf * 8] = vh;
            *(bf16x8*)&a_lo[ar * 40 + ac + hf * 8] = vl;
        }
        // stage B (split + transpose to [n][k])
#pragma unroll
        for (int p = 0; p < 4; ++p) {
#pragma unroll
            for (int q = 0; q < 4; ++q) {
                float f = ((const float*)&breg[p])[q];
                unsigned short hh = bf16_rne(f);
                int n = bf + p * 4 + q;
                b_hi[n * 40 + bk] = hh;
                b_lo[n * 40 + bk] = bf16_rne(f - bf16_to_f(hh));
            }
        }
        __syncthreads();
        if (kt + 1 < nkt) gload(kt + 1);
        // fragments + MFMA
        bf16x8 afh[4], afl[4], bfh[4], bfl[4];
        int ab = (wr * 64 + (lane & 15)) * 40 + (lane >> 4) * 8;
        int bb = (wc * 64 + (lane & 15)) * 40 + (lane >> 4) * 8;
#pragma unroll
        for (int mi = 0; mi < 4; ++mi) {
            afh[mi] = *(const bf16x8*)&a_hi[ab + mi * 16 * 40];
            afl[mi] = *(const bf16x8*)&a_lo[ab + mi * 16 * 40];
        }
#pragma unroll
        for (int nj = 0; nj < 4; ++nj) {
            bfh[nj] = *(const bf16x8*)&b_hi[bb + nj * 16 * 40];
            bfl[nj] = *(const bf16x8*)&b_lo[bb + nj * 16 * 40];
        }
#pragma unroll
        for (int mi = 0; mi < 4; ++mi)
#pragma unroll
            for (int nj = 0; nj < 4; ++nj) {
                acc[mi][nj] = __builtin_amdgcn_mfma_f32_16x16x32_bf16(afh[mi], bfh[nj], acc[mi][nj], 0, 0, 0);
                acc[mi][nj] = __builtin_amdgcn_mfma_f32_16x16x32_bf16(afh[mi], bfl[nj], acc[mi][nj], 0, 0, 0);
                acc[mi][nj] = __builtin_amdgcn_mfma_f32_16x16x32_bf16(afl[mi], bfh[nj], acc[mi][nj], 0, 0, 0);
            }
    }
    // epilogue: write Wv as pre-split hi/lo bf16 planes
#pragma unroll
    for (int mi = 0; mi < 4; ++mi)
#pragma unroll
        for (int nj = 0; nj < 4; ++nj) {
            int r0 = i0 + wr * 64 + mi * 16 + (lane >> 4) * 4;
            int c0 = f0 + wc * 64 + nj * 16 + (lane & 15);
#pragma unroll
            for (int r = 0; r < 4; ++r) {
                float f = acc[mi][nj][r];
                unsigned short hh = bf16_rne(f);
                size_t off = (size_t)(r0 + r) * Fn + c0;
                wv_hi[off] = hh;
                wv_lo[off] = bf16_rne(f - bf16_to_f(hh));
            }
        }
}

// ---------------------------------------------------------------------------
// K3: per-row softmax stats from PACKED mask; stat = (m, 1/s). grid M x 256
// ---------------------------------------------------------------------------
__global__ __launch_bounds__(256) void k_stats(const unsigned int* __restrict__ pk,
                                               const float* __restrict__ Wha,
                                               const float* __restrict__ Wta,
                                               float2* __restrict__ stat) {
    int bi = blockIdx.x;
    int b = bi >> 10;
    const float* wt = Wta + b * Nn;
    float whai = Wha[bi];
    int t = threadIdx.x;
    unsigned int word = pk[(size_t)bi * 32 + (t >> 3)];
    int sh = (t & 7) * 4;
    float4 wv = *(const float4*)&wt[t * 4];
    float e[4];
    {
        float x;
        x = whai + wv.x; x = x > 0.f ? x : ALPHA * x; e[0] = ((word >> (sh + 0)) & 1) ? x : NEGV;
        x = whai + wv.y; x = x > 0.f ? x : ALPHA * x; e[1] = ((word >> (sh + 1)) & 1) ? x : NEGV;
        x = whai + wv.z; x = x > 0.f ? x : ALPHA * x; e[2] = ((word >> (sh + 2)) & 1) ? x : NEGV;
        x = whai + wv.w; x = x > 0.f ? x : ALPHA * x; e[3] = ((word >> (sh + 3)) & 1) ? x : NEGV;
    }
    float m4 = fmaxf(fmaxf(e[0], e[1]), fmaxf(e[2], e[3]));
    __shared__ float redm[4], reds[4];
    int wave = t >> 6, lane = t & 63;
    float m = wave_reduce_max(m4);
    if (lane == 0) redm[wave] = m;
    __syncthreads();
    m = fmaxf(fmaxf(redm[0], redm[1]), fmaxf(redm[2], redm[3]));
    float s4 = __expf(e[0] - m) + __expf(e[1] - m) + __expf(e[2] - m) + __expf(e[3] - m);
    float s = wave_reduce_sum(s4);
    if (lane == 0) reds[wave] = s;
    __syncthreads();
    if (t == 0) {
        s = reds[0] + reds[1] + reds[2] + reds[3];
        stat[bi] = make_float2(m, 1.0f / s);
    }
}

// ---------------------------------------------------------------------------
// K4: h' = attention @ Wv via split-bf16 MFMA. A (att) generated on the fly
// from packed mask + Wha/Wta/stat, split hi/lo in-register; B loaded from the
// pre-split Wv planes (no conversion). Same 128x128x32 tile as K2.
// grid (Nn/128, Fn/128, Bn)
// ---------------------------------------------------------------------------
__global__ __launch_bounds__(256) void k_attn_mfma(const unsigned int* __restrict__ pk,
                                                   const float* __restrict__ Wha,
                                                   const float* __restrict__ Wta,
                                                   const float2* __restrict__ stat,
                                                   const unsigned short* __restrict__ wv_hi,
                                                   const unsigned short* __restrict__ wv_lo,
                                                   float* __restrict__ outp) {
    __shared__ __attribute__((aligned(16))) unsigned short a_hi[128 * 40];
    __shared__ __attribute__((aligned(16))) unsigned short a_lo[128 * 40];
    __shared__ __attribute__((aligned(16))) unsigned short b_hi[128 * 40];
    __shared__ __attribute__((aligned(16))) unsigned short b_lo[128 * 40];
    __shared__ __attribute__((aligned(16))) float wta_s[Nn];
    __shared__ float wha_s[128], m_s[128], rs_s[128];
    int t = threadIdx.x;
    int wave = t >> 6, lane = t & 63;
    int wr = wave >> 1, wc = wave & 1;
    int b  = blockIdx.z;
    int i0 = blockIdx.x * 128, f0 = blockIdx.y * 128;

    if (t < 128) {
        wha_s[t] = Wha[b * Nn + i0 + t];
        float2 st = stat[b * Nn + i0 + t];
        m_s[t] = st.x; rs_s[t] = st.y;
    }
    *(float4*)&wta_s[t * 4] = *(const float4*)&Wta[b * Nn + t * 4];

    f32x4 zero = {0.f, 0.f, 0.f, 0.f};
    f32x4 acc[4][4];
#pragma unroll
    for (int mi = 0; mi < 4; ++mi)
#pragma unroll
        for (int nj = 0; nj < 4; ++nj) acc[mi][nj] = zero;

    int ai = t >> 1, ajh = (t & 1) * 16;       // att: row 0..127, 16-j half
    int bk = t >> 3, bf = (t & 7) * 16;        // B: k-row 0..31, 16-col group
    const unsigned short* hbase = wv_hi + ((size_t)b * Nn + bk) * Fn + f0 + bf;
    const unsigned short* lbase = wv_lo + ((size_t)b * Nn + bk) * Fn + f0 + bf;

    unsigned int pword;
    uint4 bh0, bh1, bl0, bl1;
    auto gload = [&](int kt) {
        pword = pk[((size_t)b * Nn + i0 + ai) * 32 + kt];
        const unsigned short* hp = hbase + (size_t)kt * 32 * Fn;
        const unsigned short* lp = lbase + (size_t)kt * 32 * Fn;
        bh0 = *(const uint4*)hp; bh1 = *(const uint4*)(hp + 8);
        bl0 = *(const uint4*)lp; bl1 = *(const uint4*)(lp + 8);
    };

    gload(0);
    __syncthreads();   // wta_s / wha_s / stats ready

    for (int kt = 0; kt < Nn / 32; ++kt) {
        // generate 16 attention weights (fp32) for row ai, j = kt*32+ajh..+15
        float att[16];
        {
            float whai = wha_s[ai], mi_ = m_s[ai], rsi = rs_s[ai];
#pragma unroll
            for (int q = 0; q < 16; ++q) {
                float x = whai + wta_s[kt * 32 + ajh + q];
                x = x > 0.f ? x : ALPHA * x;
                float e = ((pword >> (ajh + q)) & 1) ? x : NEGV;
                att[q] = __expf(e - mi_) * rsi;
            }
        }
        __syncthreads();           // previous MFMA done reading LDS
        // stage A (split att)
#pragma unroll
        for (int hf = 0; hf < 2; ++hf) {
            bf16x8 vh, vl;
#pragma unroll
            for (int q = 0; q < 8; ++q) {
                float f = att[hf * 8 + q];
                unsigned short hh = bf16_rne(f);
                vh[q] = (short)hh;
                vl[q] = (short)bf16_rne(f - bf16_to_f(hh));
            }
            *(bf16x8*)&a_hi[ai * 40 + ajh + hf * 8] = vh;
            *(bf16x8*)&a_lo[ai * 40 + ajh + hf * 8] = vl;
        }
        // stage B (pre-split, transpose to [n][k])
#pragma unroll
        for (int q = 0; q < 8; ++q) {
            b_hi[(bf + q) * 40 + bk]     = ((const unsigned short*)&bh0)[q];
            b_hi[(bf + 8 + q) * 40 + bk] = ((const unsigned short*)&bh1)[q];
            b_lo[(bf + q) * 40 + bk]     = ((const unsigned short*)&bl0)[q];
            b_lo[(bf + 8 + q) * 40 + bk] = ((const unsigned short*)&bl1)[q];
        }
        __syncthreads();
        if (kt + 1 < Nn / 32) gload(kt + 1);
        // fragments + MFMA
        bf16x8 afh[4], afl[4], bfh[4], bfl[4];
        int ab = (wr * 64 + (lane & 15)) * 40 + (lane >> 4) * 8;
        int bb = (wc * 64 + (lane & 15)) * 40 + (lane >> 4) * 8;
#pragma unroll
        for (int mi = 0; mi < 4; ++mi) {
            afh[mi] = *(const bf16x8*)&a_hi[ab + mi * 16 * 40];
            afl[mi] = *(const bf16x8*)&a_lo[ab + mi * 16 * 40];
        }
#pragma unroll
        for (int nj = 0; nj < 4; ++nj) {
            bfh[nj] = *(const bf16x8*)&b_hi[bb + nj * 16 * 40];
            bfl[nj] = *(const bf16x8*)&b_lo[bb + nj * 16 * 40];
        }
#pragma unroll
        for (int mi = 0; mi < 4; ++mi)
#pragma unroll
            for (int nj = 0; nj < 4; ++nj) {
                acc[mi][nj] = __builtin_amdgcn_mfma_f32_16x16x32_bf16(afh[mi], bfh[nj], acc[mi][nj], 0, 0, 0);
                acc[mi][nj] = __builtin_amdgcn_mfma_f32_16x16x32_bf16(afh[mi], bfl[nj], acc[mi][nj], 0, 0, 0);
                acc[mi][nj] = __builtin_amdgcn_mfma_f32_16x16x32_bf16(afl[mi], bfh[nj], acc[mi][nj], 0, 0, 0);
            }
    }
    // epilogue: fp32 h' to d_out (LN+GELU kernel follows)
#pragma unroll
    for (int mi = 0; mi < 4; ++mi)
#pragma unroll
        for (int nj = 0; nj < 4; ++nj) {
            int r0 = i0 + wr * 64 + mi * 16 + (lane >> 4) * 4;
            int c0 = f0 + wc * 64 + nj * 16 + (lane & 15);
#pragma unroll
            for (int r = 0; r < 4; ++r)
                outp[((size_t)b * Nn + r0 + r) * Fn + c0] = acc[mi][nj][r];
        }
}

// ---------------------------------------------------------------------------
// K5: LayerNorm over F + exact GELU, in-place on d_out. grid M x 128
// ---------------------------------------------------------------------------
__global__ __launch_bounds__(128) void k_ln_gelu(float* __restrict__ x,
                                                 const float* __restrict__ gamma,
                                                 const float* __restrict__ beta) {
    int row = blockIdx.x;
    float* xr = x + (size_t)row * Fn;
    int t = threadIdx.x;
    float4 v = *(float4*)&xr[t * 4];
    float s = v.x + v.y + v.z + v.w;
    float q = v.x * v.x + v.y * v.y + v.z * v.z + v.w * v.w;
    s = wave_reduce_sum(s);
    q = wave_reduce_sum(q);
    __shared__ float rs[2], rq[2];
    int wave = t >> 6, lane = t & 63;
    if (lane == 0) { rs[wave] = s; rq[wave] = q; }
    __syncthreads();
    s = rs[0] + rs[1];
    q = rq[0] + rq[1];
    float mu   = s * (1.0f / Fn);
    float var  = q * (1.0f / Fn) - mu * mu;
    float rstd = rsqrtf(var + EPSV);
    float4 g  = *(const float4*)&gamma[t * 4];
    float4 be = *(const float4*)&beta[t * 4];
    auto gel = [](float xx) { return 0.5f * xx * (1.0f + erff(xx * 0.70710678118f)); };
    float y0 = (v.x - mu) * rstd * g.x + be.x;
    float y1 = (v.y - mu) * rstd * g.y + be.y;
    float y2 = (v.z - mu) * rstd * g.z + be.z;
    float y3 = (v.w - mu) * rstd * g.w + be.w;
    float4 o = {gel(y0), gel(y1), gel(y2), gel(y3)};
    *(float4*)&xr[t * 4] = o;
}

// ---------------------------------------------------------------------------
extern "C" void kernel_launch(void* const* d_in, const int* in_sizes, int n_in,
                              void* d_out, int out_size, void* d_ws, size_t ws_size,
                              hipStream_t stream) {
    const float* h1    = (const float*)d_in[0];
    const float* h2    = (const float*)d_in[1];
    const int*   adj   = (const int*)d_in[2];
    const float* W1    = (const float*)d_in[3];
    const float* W2    = (const float*)d_in[4];
    const float* W3    = (const float*)d_in[5];
    const float* a     = (const float*)d_in[6];
    const float* gamma = (const float*)d_in[7];
    const float* beta  = (const float*)d_in[8];
    float* outp = (float*)d_out;

    // workspace layout (bytes): wv planes | pack | stat | c | Wha | Wta  (~18 MB)
    unsigned short* wv_hi = (unsigned short*)d_ws;
    unsigned short* wv_lo = wv_hi + (size_t)M * Fn;
    unsigned int*   pack  = (unsigned int*)(wv_lo + (size_t)M * Fn);
    float2*         stat  = (float2*)(pack + (size_t)M * 32);
    float*          c     = (float*)(stat + M);
    float*          Wha   = c + 1024;
    float*          Wta   = Wha + M;

    hipLaunchKernelGGL(k_pack, dim3(M * 32 / 256), dim3(256), 0, stream, adj, pack);
    hipLaunchKernelGGL(k_proj_w, dim3(1024), dim3(64), 0, stream, W1, W2, a, c);
    hipLaunchKernelGGL(k_proj_h, dim3(M / 4, 2), dim3(256), 0, stream, h1, h2, c, Wha, Wta);
    hipLaunchKernelGGL(k_gemm_mfma, dim3(M / 128, Fn / 128), dim3(256), 0, stream,
                       h2, W3, wv_hi, wv_lo);
    hipLaunchKernelGGL(k_stats, dim3(M), dim3(256), 0, stream, pack, Wha, Wta, stat);
    hipLaunchKernelGGL(k_attn_mfma, dim3(Nn / 128, Fn / 128, Bn), dim3(256), 0, stream,
                       pack, Wha, Wta, stat, wv_hi, wv_lo, outp);
    hipLaunchKernelGGL(k_ln_gelu, dim3(M), dim3(128), 0, stream, outp, gamma, beta);
}

// Round 7
// 245.461 us; speedup vs baseline: 1.4852x; 1.0762x over previous
//
#include <hip/hip_runtime.h>
#include <math.h>

#define ALPHA 0.2f
#define NEGV  -9000000000000000.0f
#define EPSV  1e-5f

static constexpr int Bn = 8;
static constexpr int Nn = 1024;
static constexpr int Fn = 512;
static constexpr int M  = Bn * Nn;   // 8192 rows total

typedef __attribute__((ext_vector_type(8))) short bf16x8;
typedef __attribute__((ext_vector_type(4))) float f32x4;

__device__ inline float wave_reduce_sum(float v) {
#pragma unroll
    for (int off = 32; off; off >>= 1) v += __shfl_xor(v, off);
    return v;
}
__device__ inline float wave_reduce_max(float v) {
#pragma unroll
    for (int off = 32; off; off >>= 1) v = fmaxf(v, __shfl_xor(v, off));
    return v;
}

__device__ inline unsigned short bf16_rne(float f) {
    union { float f; unsigned int u; } v; v.f = f;
    unsigned int r = v.u + 0x7FFFu + ((v.u >> 16) & 1u);
    return (unsigned short)(r >> 16);
}
__device__ inline float bf16_to_f(unsigned short h) {
    union { unsigned int u; float f; } v; v.u = (unsigned int)h << 16;
    return v.f;
}

// ---------------------------------------------------------------------------
// K-1: pack adj into bitmask words: pk[row*32+w] bit q = adj[row*1024+w*32+q]>0
// ---------------------------------------------------------------------------
__global__ __launch_bounds__(256) void k_pack(const int* __restrict__ adj,
                                              unsigned int* __restrict__ pk) {
    int idx = blockIdx.x * 256 + threadIdx.x;
    const int* p = adj + (size_t)idx * 32;
    unsigned int m = 0;
#pragma unroll
    for (int q = 0; q < 8; ++q) {
        int4 v = *(const int4*)&p[q * 4];
        m |= (unsigned)(v.x > 0) << (q * 4 + 0);
        m |= (unsigned)(v.y > 0) << (q * 4 + 1);
        m |= (unsigned)(v.z > 0) << (q * 4 + 2);
        m |= (unsigned)(v.w > 0) << (q * 4 + 3);
    }
    pk[idx] = m;
}

// ---------------------------------------------------------------------------
// K0: c1 = W1@a1, c2 = W2@a2 (tiny)
// ---------------------------------------------------------------------------
__global__ __launch_bounds__(64) void k_proj_w(const float* __restrict__ W1,
                                               const float* __restrict__ W2,
                                               const float* __restrict__ a,
                                               float* __restrict__ c) {
    int bid = blockIdx.x, which = bid >> 9, row = bid & 511;
    const float* W  = which ? W2 : W1;
    const float* av = a + which * Fn;
    const float* wr = W + (size_t)row * Fn;
    int lane = threadIdx.x;
    float s = 0.f;
#pragma unroll
    for (int p = 0; p < 2; ++p) {
        float4 wv = *(const float4*)&wr[lane * 4 + p * 256];
        float4 a4 = *(const float4*)&av[lane * 4 + p * 256];
        s += wv.x * a4.x + wv.y * a4.y + wv.z * a4.z + wv.w * a4.w;
    }
    s = wave_reduce_sum(s);
    if (lane == 0) c[which * Fn + row] = s;
}

// ---------------------------------------------------------------------------
// K1: Wha = h1@c1 ; Wta = h2@c2 (wave per row)
// ---------------------------------------------------------------------------
__global__ __launch_bounds__(256) void k_proj_h(const float* __restrict__ h1,
                                                const float* __restrict__ h2,
                                                const float* __restrict__ c,
                                                float* __restrict__ Wha,
                                                float* __restrict__ Wta) {
    int which = blockIdx.y;
    const float* h  = which ? h2 : h1;
    const float* cv = c + which * Fn;
    float* outp = which ? Wta : Wha;
    int wave = threadIdx.x >> 6, lane = threadIdx.x & 63;
    int row  = blockIdx.x * 4 + wave;
    const float* hr = h + (size_t)row * Fn;
    float s = 0.f;
#pragma unroll
    for (int p = 0; p < 2; ++p) {
        float4 hv = *(const float4*)&hr[lane * 8 + p * 4];
        float4 c4 = *(const float4*)&cv[lane * 8 + p * 4];
        s += hv.x * c4.x + hv.y * c4.y + hv.z * c4.z + hv.w * c4.w;
    }
    s = wave_reduce_sum(s);
    if (lane == 0) outp[row] = s;
}

// ---------------------------------------------------------------------------
// K2a: w3T_hi/lo[f][k] = split(W3[k][f]) — 32x32 LDS tile transpose, grid(16,16)
// ---------------------------------------------------------------------------
__global__ __launch_bounds__(256) void k_w3t(const float* __restrict__ W3,
                                             unsigned short* __restrict__ hi,
                                             unsigned short* __restrict__ lo) {
    __shared__ float tile[32][33];
    int kt = blockIdx.x * 32, ft = blockIdx.y * 32;
    int c = threadIdx.x & 31, r = threadIdx.x >> 5;   // r 0..7
#pragma unroll
    for (int s = 0; s < 4; ++s)
        tile[r + s * 8][c] = W3[(size_t)(kt + r + s * 8) * Fn + ft + c];
    __syncthreads();
#pragma unroll
    for (int s = 0; s < 4; ++s) {
        float f = tile[c][r + s * 8];
        unsigned short h = bf16_rne(f);
        size_t o = (size_t)(ft + r + s * 8) * Fn + kt + c;
        hi[o] = h;
        lo[o] = bf16_rne(f - bf16_to_f(h));
    }
}

// ---------------------------------------------------------------------------
// K2b: Wv = h2 @ W3, register-direct MFMA (no per-tile LDS staging).
// A = h2 (fp32->bf16 in reg), B = w3T hi/lo planes (direct 16B loads).
// 2 MFMA terms: a_hi*b_hi + a_hi*b_lo. Output: wvT_hi/lo[b][f][k] via LDS bounce.
// Block 256 thr = 4 waves; tile 128 rows x 64 f. grid (M/128=64, Fn/64=8).
// Same-row blocks (varying f) share h2 via same-XCD L2 (bid%8 = bx%8).
// ---------------------------------------------------------------------------
__global__ __launch_bounds__(256) void k_gemm2(const float* __restrict__ h2,
                                               const unsigned short* __restrict__ w3h,
                                               const unsigned short* __restrict__ w3l,
                                               unsigned short* __restrict__ wvh,
                                               unsigned short* __restrict__ wvl) {
    __shared__ float etile[64 * 132];
    int t = threadIdx.x, wave = t >> 6, lane = t & 63;
    int l15 = lane & 15, l16 = lane >> 4;
    int i0 = blockIdx.x * 128, f0 = blockIdx.y * 64;
    int wr = wave;                         // rows wr*32 .. wr*32+31

    f32x4 acc[2][4];
#pragma unroll
    for (int mi = 0; mi < 2; ++mi)
#pragma unroll
        for (int nj = 0; nj < 4; ++nj) acc[mi][nj] = (f32x4){0.f, 0.f, 0.f, 0.f};

    const float* a0base = h2 + (size_t)(i0 + wr * 32 + l15) * Fn + l16 * 8;
    const float* a1base = a0base + 16 * Fn;
    const unsigned short* bhb = w3h + (size_t)(f0 + l15) * Fn + l16 * 8;
    const unsigned short* blb = w3l + (size_t)(f0 + l15) * Fn + l16 * 8;

#pragma unroll 2
    for (int kt = 0; kt < Fn / 32; ++kt) {
        bf16x8 bh[4], bl[4];
#pragma unroll
        for (int nj = 0; nj < 4; ++nj) {
            bh[nj] = *(const bf16x8*)(bhb + (size_t)nj * 16 * Fn + kt * 32);
            bl[nj] = *(const bf16x8*)(blb + (size_t)nj * 16 * Fn + kt * 32);
        }
        float4 v0 = *(const float4*)(a0base + kt * 32);
        float4 v1 = *(const float4*)(a0base + kt * 32 + 4);
        float4 v2 = *(const float4*)(a1base + kt * 32);
        float4 v3 = *(const float4*)(a1base + kt * 32 + 4);
        bf16x8 a0, a1;
        {
            const float* f0p = (const float*)&v0;
            const float* f1p = (const float*)&v2;
#pragma unroll
            for (int q = 0; q < 4; ++q) {
                a0[q] = (short)bf16_rne(f0p[q]);
                a1[q] = (short)bf16_rne(f1p[q]);
            }
            const float* g0p = (const float*)&v1;
            const float* g1p = (const float*)&v3;
#pragma unroll
            for (int q = 0; q < 4; ++q) {
                a0[4 + q] = (short)bf16_rne(g0p[q]);
                a1[4 + q] = (short)bf16_rne(g1p[q]);
            }
        }
#pragma unroll
        for (int nj = 0; nj < 4; ++nj) {
            acc[0][nj] = __builtin_amdgcn_mfma_f32_16x16x32_bf16(a0, bh[nj], acc[0][nj], 0, 0, 0);
            acc[0][nj] = __builtin_amdgcn_mfma_f32_16x16x32_bf16(a0, bl[nj], acc[0][nj], 0, 0, 0);
            acc[1][nj] = __builtin_amdgcn_mfma_f32_16x16x32_bf16(a1, bh[nj], acc[1][nj], 0, 0, 0);
            acc[1][nj] = __builtin_amdgcn_mfma_f32_16x16x32_bf16(a1, bl[nj], acc[1][nj], 0, 0, 0);
        }
    }
    // epilogue: transpose via LDS, write wvT[b][f][n] split hi/lo (coalesced)
#pragma unroll
    for (int mi = 0; mi < 2; ++mi)
#pragma unroll
        for (int nj = 0; nj < 4; ++nj) {
            int nloc = wr * 32 + mi * 16 + l16 * 4;
            int floc = nj * 16 + l15;
            *(float4*)&etile[floc * 132 + nloc] = *(float4*)&acc[mi][nj];
        }
    __syncthreads();
    {
        int floc = t >> 2, n0 = (t & 3) * 32;
        int b = i0 >> 10, nb = i0 & 1023;
        unsigned short* oh = wvh + ((size_t)b * Fn + f0 + floc) * Nn + nb + n0;
        unsigned short* ol = wvl + ((size_t)b * Fn + f0 + floc) * Nn + nb + n0;
        const float* src = &etile[floc * 132 + n0];
        bf16x8 rh[4], rl[4];
#pragma unroll
        for (int s = 0; s < 4; ++s) {
#pragma unroll
            for (int q = 0; q < 8; ++q) {
                float f = src[s * 8 + q];
                unsigned short h = bf16_rne(f);
                rh[s][q] = (short)h;
                rl[s][q] = (short)bf16_rne(f - bf16_to_f(h));
            }
        }
#pragma unroll
        for (int s = 0; s < 4; ++s) {
            *(bf16x8*)(oh + s * 8) = rh[s];
            *(bf16x8*)(ol + s * 8) = rl[s];
        }
    }
}

// ---------------------------------------------------------------------------
// K3: per-row softmax stats from packed mask; stat = (m, 1/s). grid M x 256
// ---------------------------------------------------------------------------
__global__ __launch_bounds__(256) void k_stats(const unsigned int* __restrict__ pk,
                                               const float* __restrict__ Wha,
                                               const float* __restrict__ Wta,
                                               float2* __restrict__ stat) {
    int bi = blockIdx.x;
    int b = bi >> 10;
    const float* wt = Wta + b * Nn;
    float whai = Wha[bi];
    int t = threadIdx.x;
    unsigned int word = pk[(size_t)bi * 32 + (t >> 3)];
    int sh = (t & 7) * 4;
    float4 wv = *(const float4*)&wt[t * 4];
    float e[4];
    {
        float x;
        x = whai + wv.x; x = fmaxf(x, ALPHA * x); e[0] = ((word >> (sh + 0)) & 1) ? x : NEGV;
        x = whai + wv.y; x = fmaxf(x, ALPHA * x); e[1] = ((word >> (sh + 1)) & 1) ? x : NEGV;
        x = whai + wv.z; x = fmaxf(x, ALPHA * x); e[2] = ((word >> (sh + 2)) & 1) ? x : NEGV;
        x = whai + wv.w; x = fmaxf(x, ALPHA * x); e[3] = ((word >> (sh + 3)) & 1) ? x : NEGV;
    }
    float m4 = fmaxf(fmaxf(e[0], e[1]), fmaxf(e[2], e[3]));
    __shared__ float redm[4], reds[4];
    int wave = t >> 6, lane = t & 63;
    float m = wave_reduce_max(m4);
    if (lane == 0) redm[wave] = m;
    __syncthreads();
    m = fmaxf(fmaxf(redm[0], redm[1]), fmaxf(redm[2], redm[3]));
    float s4 = __expf(e[0] - m) + __expf(e[1] - m) + __expf(e[2] - m) + __expf(e[3] - m);
    float s = wave_reduce_sum(s4);
    if (lane == 0) reds[wave] = s;
    __syncthreads();
    if (t == 0) {
        s = reds[0] + reds[1] + reds[2] + reds[3];
        stat[bi] = make_float2(m, 1.0f / s);
    }
}

// ---------------------------------------------------------------------------
// K4: h' = attention @ Wv, fully register-direct MFMA.
// A-fragments generated per-lane (lane owns m=lane&15, k=(lane>>4)*8+j) from
// LDS-resident Wha/Wta/stat/pk (staged once; NO barriers in K-loop).
// B-fragments: direct 16B loads from wvT hi/lo planes.
// 2 MFMA terms (att bf16, V split hi+lo); 1/s folded into epilogue.
// Block 256 thr = 4 waves; tile 128 i x 64 f. grid (f=8, i=8, b=8):
// same-f blocks (sharing wvT panel) land on one XCD (bid%8 = fx).
// ---------------------------------------------------------------------------
__global__ __launch_bounds__(256) void k_attn2(const unsigned int* __restrict__ pk,
                                               const float* __restrict__ Wha,
                                               const float* __restrict__ Wta,
                                               const float2* __restrict__ stat,
                                               const unsigned short* __restrict__ wvh,
                                               const unsigned short* __restrict__ wvl,
                                               float* __restrict__ outp) {
    __shared__ unsigned int pkt[32 * 128];     // [word][row] transposed
    __shared__ float wta_s[Nn];
    __shared__ float wha_s[128], m_s[128], rs_s[128];
    int t = threadIdx.x, wave = t >> 6, lane = t & 63;
    int l15 = lane & 15, l16 = lane >> 4;
    int f0 = blockIdx.x * 64, i0 = blockIdx.y * 128, b = blockIdx.z;

    {   // stage pk (transposed), wta, wha/m/rs — once
        int r = t >> 1, half = t & 1;
        const unsigned int* src = pk + ((size_t)(b * Nn + i0 + r)) * 32 + half * 16;
        uint4 w0 = *(const uint4*)src, w1 = *(const uint4*)(src + 4);
        uint4 w2 = *(const uint4*)(src + 8), w3 = *(const uint4*)(src + 12);
        const unsigned int* ww = (const unsigned int*)&w0;  // w0..w3 contiguous? no — store per vec
        unsigned int wv_[16] = {w0.x, w0.y, w0.z, w0.w, w1.x, w1.y, w1.z, w1.w,
                                w2.x, w2.y, w2.z, w2.w, w3.x, w3.y, w3.z, w3.w};
        (void)ww;
#pragma unroll
        for (int w = 0; w < 16; ++w) pkt[(half * 16 + w) * 128 + r] = wv_[w];
        *(float4*)&wta_s[t * 4] = *(const float4*)&Wta[b * Nn + t * 4];
        if (t < 128) {
            wha_s[t] = Wha[b * Nn + i0 + t];
            float2 st = stat[b * Nn + i0 + t];
            m_s[t] = st.x; rs_s[t] = st.y;
        }
    }
    __syncthreads();

    int wr = wave;
    float whaA = wha_s[wr * 32 + l15],      mA = m_s[wr * 32 + l15];
    float whaB = wha_s[wr * 32 + 16 + l15], mB = m_s[wr * 32 + 16 + l15];
    const unsigned short* bhb = wvh + ((size_t)b * Fn + f0 + l15) * Nn + l16 * 8;
    const unsigned short* blb = wvl + ((size_t)b * Fn + f0 + l15) * Nn + l16 * 8;

    f32x4 acc[2][4];
#pragma unroll
    for (int mi = 0; mi < 2; ++mi)
#pragma unroll
        for (int nj = 0; nj < 4; ++nj) acc[mi][nj] = (f32x4){0.f, 0.f, 0.f, 0.f};

#pragma unroll 2
    for (int kt = 0; kt < Nn / 32; ++kt) {
        // B loads first (latency hides under att-gen VALU below)
        bf16x8 bh[4], bl[4];
#pragma unroll
        for (int nj = 0; nj < 4; ++nj) {
            bh[nj] = *(const bf16x8*)(bhb + (size_t)nj * 16 * Nn + kt * 32);
            bl[nj] = *(const bf16x8*)(blb + (size_t)nj * 16 * Nn + kt * 32);
        }
        // generate A fragments in-register
        unsigned int shA = pkt[kt * 128 + wr * 32 + l15] >> (l16 * 8);
        unsigned int shB = pkt[kt * 128 + wr * 32 + 16 + l15] >> (l16 * 8);
        float4 wq0 = *(const float4*)&wta_s[kt * 32 + l16 * 8];
        float4 wq1 = *(const float4*)&wta_s[kt * 32 + l16 * 8 + 4];
        float wq[8] = {wq0.x, wq0.y, wq0.z, wq0.w, wq1.x, wq1.y, wq1.z, wq1.w};
        bf16x8 a0, a1;
#pragma unroll
        for (int q = 0; q < 8; ++q) {
            float xA = whaA + wq[q];
            xA = fmaxf(xA, ALPHA * xA);
            float pA = __expf(xA - mA);
            pA = ((shA >> q) & 1) ? pA : 0.0f;
            a0[q] = (short)bf16_rne(pA);
            float xB = whaB + wq[q];
            xB = fmaxf(xB, ALPHA * xB);
            float pB = __expf(xB - mB);
            pB = ((shB >> q) & 1) ? pB : 0.0f;
            a1[q] = (short)bf16_rne(pB);
        }
#pragma unroll
        for (int nj = 0; nj < 4; ++nj) {
            acc[0][nj] = __builtin_amdgcn_mfma_f32_16x16x32_bf16(a0, bh[nj], acc[0][nj], 0, 0, 0);
            acc[0][nj] = __builtin_amdgcn_mfma_f32_16x16x32_bf16(a0, bl[nj], acc[0][nj], 0, 0, 0);
            acc[1][nj] = __builtin_amdgcn_mfma_f32_16x16x32_bf16(a1, bh[nj], acc[1][nj], 0, 0, 0);
            acc[1][nj] = __builtin_amdgcn_mfma_f32_16x16x32_bf16(a1, bl[nj], acc[1][nj], 0, 0, 0);
        }
    }
    // epilogue: scale by 1/s per row, store fp32
#pragma unroll
    for (int mi = 0; mi < 2; ++mi)
#pragma unroll
        for (int nj = 0; nj < 4; ++nj) {
#pragma unroll
            for (int r = 0; r < 4; ++r) {
                int rloc = wr * 32 + mi * 16 + l16 * 4 + r;
                float rs = rs_s[rloc];
                outp[((size_t)b * Nn + i0 + rloc) * Fn + f0 + nj * 16 + l15] =
                    rs * acc[mi][nj][r];
            }
        }
}

// ---------------------------------------------------------------------------
// K5: LayerNorm over F + exact GELU, in-place on d_out. grid M x 128
// ---------------------------------------------------------------------------
__global__ __launch_bounds__(128) void k_ln_gelu(float* __restrict__ x,
                                                 const float* __restrict__ gamma,
                                                 const float* __restrict__ beta) {
    int row = blockIdx.x;
    float* xr = x + (size_t)row * Fn;
    int t = threadIdx.x;
    float4 v = *(float4*)&xr[t * 4];
    float s = v.x + v.y + v.z + v.w;
    float q = v.x * v.x + v.y * v.y + v.z * v.z + v.w * v.w;
    s = wave_reduce_sum(s);
    q = wave_reduce_sum(q);
    __shared__ float rs[2], rq[2];
    int wave = t >> 6, lane = t & 63;
    if (lane == 0) { rs[wave] = s; rq[wave] = q; }
    __syncthreads();
    s = rs[0] + rs[1];
    q = rq[0] + rq[1];
    float mu   = s * (1.0f / Fn);
    float var  = q * (1.0f / Fn) - mu * mu;
    float rstd = rsqrtf(var + EPSV);
    float4 g  = *(const float4*)&gamma[t * 4];
    float4 be = *(const float4*)&beta[t * 4];
    auto gel = [](float xx) { return 0.5f * xx * (1.0f + erff(xx * 0.70710678118f)); };
    float y0 = (v.x - mu) * rstd * g.x + be.x;
    float y1 = (v.y - mu) * rstd * g.y + be.y;
    float y2 = (v.z - mu) * rstd * g.z + be.z;
    float y3 = (v.w - mu) * rstd * g.w + be.w;
    float4 o = {gel(y0), gel(y1), gel(y2), gel(y3)};
    *(float4*)&xr[t * 4] = o;
}

// ---------------------------------------------------------------------------
extern "C" void kernel_launch(void* const* d_in, const int* in_sizes, int n_in,
                              void* d_out, int out_size, void* d_ws, size_t ws_size,
                              hipStream_t stream) {
    const float* h1    = (const float*)d_in[0];
    const float* h2    = (const float*)d_in[1];
    const int*   adj   = (const int*)d_in[2];
    const float* W1    = (const float*)d_in[3];
    const float* W2    = (const float*)d_in[4];
    const float* W3    = (const float*)d_in[5];
    const float* a     = (const float*)d_in[6];
    const float* gamma = (const float*)d_in[7];
    const float* beta  = (const float*)d_in[8];
    float* outp = (float*)d_out;

    // workspace: wvT hi/lo (16.8MB) | w3T hi/lo (1MB) | pack (1MB) | stat | c | Wha | Wta
    unsigned short* wvh  = (unsigned short*)d_ws;
    unsigned short* wvl  = wvh + (size_t)M * Fn;
    unsigned short* w3h  = wvl + (size_t)M * Fn;
    unsigned short* w3l  = w3h + (size_t)Fn * Fn;
    unsigned int*   pack = (unsigned int*)(w3l + (size_t)Fn * Fn);
    float2*         stat = (float2*)(pack + (size_t)M * 32);
    float*          c    = (float*)(stat + M);
    float*          Wha  = c + 1024;
    float*          Wta  = Wha + M;

    hipLaunchKernelGGL(k_pack, dim3(M * 32 / 256), dim3(256), 0, stream, adj, pack);
    hipLaunchKernelGGL(k_proj_w, dim3(1024), dim3(64), 0, stream, W1, W2, a, c);
    hipLaunchKernelGGL(k_proj_h, dim3(M / 4, 2), dim3(256), 0, stream, h1, h2, c, Wha, Wta);
    hipLaunchKernelGGL(k_w3t, dim3(16, 16), dim3(256), 0, stream, W3, w3h, w3l);
    hipLaunchKernelGGL(k_gemm2, dim3(M / 128, Fn / 64), dim3(256), 0, stream,
                       h2, w3h, w3l, wvh, wvl);
    hipLaunchKernelGGL(k_stats, dim3(M), dim3(256), 0, stream, pack, Wha, Wta, stat);
    hipLaunchKernelGGL(k_attn2, dim3(Fn / 64, Nn / 128, Bn), dim3(256), 0, stream,
                       pack, Wha, Wta, stat, wvh, wvl, outp);
    hipLaunchKernelGGL(k_ln_gelu, dim3(M), dim3(128), 0, stream, outp, gamma, beta);
}